// Round 8
// baseline (264.441 us; speedup 1.0000x reference)
//
#include <hip/hip_runtime.h>
#include <hip/hip_bf16.h>

// CausalSelfAttention: B=4, T=2048, D=1024, H=16, DH=64.
// Dtypes (established): inputs fp32, output fp32 (absmax thresh 0.075).
// R17: attn restructure for latency-bound regime (R16 counters: no pipe
// saturated, conflicts 0, occupancy 32%).
//  - QBLK 64 -> 128: 8 waves (512 thr), each staged K/V tile serves 2x the
//    q rows -> staging + barriers per q halved. LDS 42.5KB -> 3 blocks/CU
//    = 24 waves/CU (was 16).
//  - pa/31-pa pairing dropped; grid (16 qt x 64 bh), qt descending (LPT);
//    scheduler backfills short blocks.
//  - per-q math and accumulation order unchanged -> bit-identical output.
//  - wave-level skip of fully-masked tiles; per-wave mask-path selection.
// R17b: cvt_bf16 + 2x transpose_bf fused into one `prep` launch (6 -> 4
// kernels; tests the ~11us/launch gap seen as total - sum(dispatches)).
// GEMMs unchanged from R16.

namespace {
constexpr int kB = 4, kT = 2048, kD = 1024, kH = 16;
constexpr int kM = kB * kT;  // 8192
constexpr int kNq = 3 * kD;  // 3072
constexpr float kS = 0.180336880f;  // log2(e)/sqrt(64), folded into Q weights
}  // namespace

typedef unsigned short u16;
typedef short bf16x8 __attribute__((ext_vector_type(8)));  // 8 bf16, 4 VGPR
typedef float f32x4 __attribute__((ext_vector_type(4)));

__device__ __forceinline__ u16 f2bf(float f) {
  unsigned int u = __float_as_uint(f);
  u += 0x7fffu + ((u >> 16) & 1u);  // round-to-nearest-even
  return (u16)(u >> 16);
}
__device__ __forceinline__ unsigned int pack2(float a, float b) {
  return (unsigned int)f2bf(a) | ((unsigned int)f2bf(b) << 16);
}
// packed f32x2 -> bf16x2 in one VALU op (RNE)
__device__ __forceinline__ unsigned int cvtpk(float a, float b) {
  unsigned int r;
  asm("v_cvt_pk_bf16_f32 %0, %1, %2" : "=v"(r) : "v"(a), "v"(b));
  return r;
}

// async 16B global -> LDS (wave-uniform base + lane*16 semantics)
__device__ __forceinline__ void gload16(const u16* g, u16* l) {
  __builtin_amdgcn_global_load_lds(
      (const __attribute__((address_space(1))) unsigned int*)(uintptr_t)g,
      (__attribute__((address_space(3))) unsigned int*)(uintptr_t)l, 16, 0, 0);
}

// Fused prep: blocks [0,4096) x->bf16 cvt; [4096,7168) w_qkv transpose
// (kS-folded on Q cols); [7168,8192) w_out transpose.
__global__ __launch_bounds__(256) void prep(const float* __restrict__ x,
                                            u16* __restrict__ xb,
                                            const float* __restrict__ wq,
                                            u16* __restrict__ wqT,
                                            const float* __restrict__ wo,
                                            u16* __restrict__ woT) {
  __shared__ float T[32][33];
  const int tid = threadIdx.x;
  const int id = blockIdx.x;
  if (id < 4096) {  // cvt: 8 elems/thread
    const size_t i = ((size_t)id * 256 + tid) * 8;
    const float4 v0 = *(const float4*)(x + i);
    const float4 v1 = *(const float4*)(x + i + 4);
    uint4 p;
    p.x = pack2(v0.x, v0.y);
    p.y = pack2(v0.z, v0.w);
    p.z = pack2(v1.x, v1.y);
    p.w = pack2(v1.z, v1.w);
    *(uint4*)(xb + i) = p;
    return;
  }
  const float* W;
  u16* WT;
  int N, nscale, nb, kb;
  if (id < 4096 + 3072) {
    const int t = id - 4096;  // grid (96, 32)
    W = wq; WT = wqT; N = kNq; nscale = kD;
    nb = (t % 96) * 32; kb = (t / 96) * 32;
  } else {
    const int t = id - 7168;  // grid (32, 32)
    W = wo; WT = woT; N = kD; nscale = 0;
    nb = (t & 31) * 32; kb = (t >> 5) * 32;
  }
  const int r = tid >> 3, c = (tid & 7) * 4;
  const float4 v = *(const float4*)&W[(size_t)(kb + r) * N + nb + c];
  T[r][c + 0] = v.x;
  T[r][c + 1] = v.y;
  T[r][c + 2] = v.z;
  T[r][c + 3] = v.w;
  __syncthreads();
  const float s = (nb + r < nscale) ? kS : 1.0f;
  uint2 p;
  p.x = pack2(T[c + 0][r] * s, T[c + 1][r] * s);
  p.y = pack2(T[c + 2][r] * s, T[c + 3][r] * s);
  *(uint2*)&WT[(size_t)(nb + r) * kD + kb + c] = p;
}

// ---------------------------------------------------------------------------
// gemm256b: 256x256 block, 8 waves x (128x64) wave tile (unchanged from R16).
// ---------------------------------------------------------------------------
template <bool F32OUT>
__global__ __launch_bounds__(512, 2) void gemm256b(const u16* __restrict__ A,
                                                   const u16* __restrict__ BT,
                                                   void* __restrict__ Cv,
                                                   int lda, int ldc) {
  __shared__ u16 As[2][256 * 64];
  __shared__ u16 Bs[2][256 * 64];
  constexpr int NT = kD / 64;  // 16 K-tiles
  const int tid = threadIdx.x;
  const int wid = tid >> 6, lane = tid & 63;
  const int col = lane & 15, quad = lane >> 4;
  const int wm_ = wid >> 2, wn_ = wid & 3;  // 2(M) x 4(N) waves

  const int nwg = gridDim.x * gridDim.y;
  int flat = blockIdx.y * gridDim.x + blockIdx.x;
  flat = (flat & 7) * (nwg >> 3) + (flat >> 3);
  const int n0 = (flat % gridDim.x) * 256;
  const int m0 = (flat / gridDim.x) * 256;

  const int srow = tid >> 3;                      // 0..63
  const int scol8 = (tid & 7) * 8;                // storage chunk (elems)
  const int gch8 = ((tid & 7) ^ (srow & 7)) * 8;  // swizzled global chunk
  const u16* const Ag = A + (size_t)(m0 + srow) * lda + gch8;
  const u16* const Bg = BT + (size_t)(n0 + srow) * kD + gch8;

  f32x4 acc[8][4];
#pragma unroll
  for (int i = 0; i < 8; ++i)
#pragma unroll
    for (int j = 0; j < 4; ++j) acc[i][j] = (f32x4){0.f, 0.f, 0.f, 0.f};

#define STAGE_AH(buf, half, k0)                                      \
  do {                                                               \
    gload16(Ag + (size_t)((half)*128) * lda + (k0),                  \
            &As[buf][((half)*128 + srow) * 64 + scol8]);             \
    gload16(Ag + (size_t)((half)*128 + 64) * lda + (k0),             \
            &As[buf][((half)*128 + 64 + srow) * 64 + scol8]);        \
  } while (0)
#define STAGE_BH(buf, half, k0)                                      \
  do {                                                               \
    gload16(Bg + (size_t)((half)*128) * kD + (k0),                   \
            &Bs[buf][((half)*128 + srow) * 64 + scol8]);             \
    gload16(Bg + (size_t)((half)*128 + 64) * kD + (k0),              \
            &Bs[buf][((half)*128 + 64 + srow) * 64 + scol8]);        \
  } while (0)

  // prologue: AT0,BT0,BB0 complete; AB0 (2 loads) left in flight
  STAGE_AH(0, 0, 0);
  STAGE_BH(0, 0, 0);
  STAGE_BH(0, 1, 0);
  STAGE_AH(0, 1, 0);
  asm volatile("s_waitcnt vmcnt(2)" ::: "memory");
  __builtin_amdgcn_s_barrier();

  for (int t = 0; t < NT; ++t) {
    const int cur = t & 1, nxt = cur ^ 1;
    const u16* Ac = &As[cur][0];
    const u16* Bc = &Bs[cur][0];
    const int k1 = (t + 1) * 64;
    const bool pf = (t + 1 < NT);
    bf16x8 af[4], bv[4];

#define READ_A(KS, MH)                                                        \
  do {                                                                        \
    _Pragma("unroll") for (int mi = 0; mi < 4; ++mi) {                        \
      const int r = (MH)*128 + wm_ * 64 + mi * 16 + col;                      \
      af[mi] =                                                                \
          *(const bf16x8*)&Ac[r * 64 + ((((KS)*4 + quad) ^ (r & 7)) * 8)];    \
    }                                                                         \
  } while (0)
#define READ_B(KS)                                                            \
  do {                                                                        \
    _Pragma("unroll") for (int ni = 0; ni < 4; ++ni) {                        \
      const int r = wn_ * 64 + ni * 16 + col;                                 \
      bv[ni] =                                                                \
          *(const bf16x8*)&Bc[r * 64 + ((((KS)*4 + quad) ^ (r & 7)) * 8)];    \
    }                                                                         \
  } while (0)
#define MFMA16(MH)                                                            \
  do {                                                                        \
    __builtin_amdgcn_s_setprio(1);                                            \
    _Pragma("unroll") for (int mi = 0; mi < 4; ++mi)                          \
        _Pragma("unroll") for (int ni = 0; ni < 4; ++ni) acc[(MH)*4 + mi][ni] \
        = __builtin_amdgcn_mfma_f32_16x16x32_bf16(af[mi], bv[ni],             \
                                                  acc[(MH)*4 + mi][ni], 0, 0, \
                                                  0);                         \
    __builtin_amdgcn_s_setprio(0);                                            \
  } while (0)

    // P0: ks0, M-half0, +B(ks0); stage AT(t+1)
    READ_A(0, 0);
    READ_B(0);
    if (pf) STAGE_AH(nxt, 0, k1);
    __builtin_amdgcn_s_barrier();
    asm volatile("s_waitcnt lgkmcnt(0)" ::: "memory");
    MFMA16(0);
    if (pf)
      asm volatile("s_waitcnt vmcnt(2)" ::: "memory");  // AB(t) ready
    else
      asm volatile("s_waitcnt vmcnt(0)" ::: "memory");
    __builtin_amdgcn_s_barrier();

    // P1: ks0, M-half1 (reuse bv); stage BT(t+1)
    READ_A(0, 1);
    if (pf) STAGE_BH(nxt, 0, k1);
    __builtin_amdgcn_s_barrier();
    asm volatile("s_waitcnt lgkmcnt(0)" ::: "memory");
    MFMA16(1);
    __builtin_amdgcn_s_barrier();

    // P2: ks1, M-half0, +B(ks1); stage BB(t+1)
    READ_A(1, 0);
    READ_B(1);
    if (pf) STAGE_BH(nxt, 1, k1);
    __builtin_amdgcn_s_barrier();
    asm volatile("s_waitcnt lgkmcnt(0)" ::: "memory");
    MFMA16(0);
    __builtin_amdgcn_s_barrier();

    // P3: ks1, M-half1; stage AB(t+1)
    READ_A(1, 1);
    if (pf) STAGE_AH(nxt, 1, k1);
    __builtin_amdgcn_s_barrier();
    asm volatile("s_waitcnt lgkmcnt(0)" ::: "memory");
    MFMA16(1);
    if (pf)
      asm volatile("s_waitcnt vmcnt(2)" ::: "memory");  // AT,BT,BB(t+1) done
    __builtin_amdgcn_s_barrier();

#undef READ_A
#undef READ_B
#undef MFMA16
  }
#undef STAGE_AH
#undef STAGE_BH

#pragma unroll
  for (int mig = 0; mig < 8; ++mig) {
    const int row =
        m0 + (mig >> 2) * 128 + wm_ * 64 + (mig & 3) * 16 + quad * 4;
#pragma unroll
    for (int reg = 0; reg < 4; ++reg) {
#pragma unroll
      for (int nig = 0; nig < 4; ++nig) {
        const int cc = n0 + wn_ * 64 + nig * 16 + col;
        if (F32OUT)
          ((float*)Cv)[(size_t)(row + reg) * ldc + cc] = acc[mig][nig][reg];
        else
          ((u16*)Cv)[(size_t)(row + reg) * ldc + cc] = f2bf(acc[mig][nig][reg]);
      }
    }
  }
}

// ---------------------------------------------------------------------------
// 256(M)x128(N) 8-wave GEMM (unchanged from R14) -- gemm2 (256 blocks).
// ---------------------------------------------------------------------------
template <bool F32OUT>
__global__ __launch_bounds__(512, 2) void gemm_mt(const u16* __restrict__ A,
                                                  const u16* __restrict__ BT,
                                                  void* __restrict__ Cv,
                                                  int lda, int ldc) {
  __shared__ u16 As[2][256 * 64];
  __shared__ u16 Bs[2][128 * 64];
  constexpr int NT = kD / 64;  // 16 K-tiles
  const int tid = threadIdx.x;
  const int wid = tid >> 6, lane = tid & 63;
  const int col = lane & 15, quad = lane >> 4;
  const int wm_ = wid >> 2, wn_ = wid & 3;

  const int nwg = gridDim.x * gridDim.y;
  int flat = blockIdx.y * gridDim.x + blockIdx.x;
  flat = (flat & 7) * (nwg >> 3) + (flat >> 3);
  const int n0 = (flat % gridDim.x) * 128;
  const int m0 = (flat / gridDim.x) * 256;

  const int srow = tid >> 3;                      // 0..63
  const int scol8 = (tid & 7) * 8;                // storage chunk (elems)
  const int gch8 = ((tid & 7) ^ (srow & 7)) * 8;  // swizzled global chunk
  const u16* const Ag = A + (size_t)(m0 + srow) * lda + gch8;
  const u16* const Bg = BT + (size_t)(n0 + srow) * kD + gch8;

  f32x4 acc[8][2];
#pragma unroll
  for (int i = 0; i < 8; ++i)
#pragma unroll
    for (int j = 0; j < 2; ++j) acc[i][j] = (f32x4){0.f, 0.f, 0.f, 0.f};

#define STAGE_AH(buf, half, k0)                                      \
  do {                                                               \
    gload16(Ag + (size_t)((half)*128) * lda + (k0),                  \
            &As[buf][((half)*128 + srow) * 64 + scol8]);             \
    gload16(Ag + (size_t)((half)*128 + 64) * lda + (k0),             \
            &As[buf][((half)*128 + 64 + srow) * 64 + scol8]);        \
  } while (0)
#define STAGE_BF(buf, k0)                                            \
  do {                                                               \
    gload16(Bg + (size_t)(k0), &Bs[buf][srow * 64 + scol8]);         \
    gload16(Bg + (size_t)64 * kD + (k0),                             \
            &Bs[buf][(64 + srow) * 64 + scol8]);                     \
  } while (0)

  STAGE_AH(0, 0, 0);
  STAGE_BF(0, 0);
  STAGE_AH(0, 1, 0);
  STAGE_AH(1, 0, 64);
  STAGE_BF(1, 64);
  asm volatile("s_waitcnt vmcnt(4)" ::: "memory");
  __builtin_amdgcn_s_barrier();

  for (int t = 0; t < NT; ++t) {
    const int cur = t & 1;
    const u16* Ac = &As[cur][0];
    const u16* Bc = &Bs[cur][0];
    bf16x8 af[4][2], bv[2][2];

#pragma unroll
    for (int mi = 0; mi < 4; ++mi) {
      const int r = wm_ * 64 + mi * 16 + col;
#pragma unroll
      for (int ks = 0; ks < 2; ++ks)
        af[mi][ks] =
            *(const bf16x8*)&Ac[r * 64 + (((ks * 4 + quad) ^ (r & 7)) * 8)];
    }
#pragma unroll
    for (int ni = 0; ni < 2; ++ni) {
      const int r = wn_ * 32 + ni * 16 + col;
#pragma unroll
      for (int ks = 0; ks < 2; ++ks)
        bv[ni][ks] =
            *(const bf16x8*)&Bc[r * 64 + (((ks * 4 + quad) ^ (r & 7)) * 8)];
    }
    if (t + 1 < NT) STAGE_AH(cur ^ 1, 1, (t + 1) * 64);
    __builtin_amdgcn_s_barrier();
    asm volatile("s_waitcnt lgkmcnt(0)" ::: "memory");
    __builtin_amdgcn_s_setprio(1);
#pragma unroll
    for (int mi = 0; mi < 4; ++mi)
#pragma unroll
      for (int ni = 0; ni < 2; ++ni)
#pragma unroll
        for (int ks = 0; ks < 2; ++ks)
          acc[mi][ni] = __builtin_amdgcn_mfma_f32_16x16x32_bf16(
              af[mi][ks], bv[ni][ks], acc[mi][ni], 0, 0, 0);
    __builtin_amdgcn_s_setprio(0);
    if (t + 1 < NT)
      asm volatile("s_waitcnt vmcnt(6)" ::: "memory");
    else
      asm volatile("s_waitcnt vmcnt(0)" ::: "memory");
    __builtin_amdgcn_s_barrier();

#pragma unroll
    for (int mi = 0; mi < 4; ++mi) {
      const int r = 128 + wm_ * 64 + mi * 16 + col;
#pragma unroll
      for (int ks = 0; ks < 2; ++ks)
        af[mi][ks] =
            *(const bf16x8*)&Ac[r * 64 + (((ks * 4 + quad) ^ (r & 7)) * 8)];
    }
    if (t + 2 < NT) {
      STAGE_AH(cur, 0, (t + 2) * 64);
      STAGE_BF(cur, (t + 2) * 64);
    }
    __builtin_amdgcn_s_barrier();
    asm volatile("s_waitcnt lgkmcnt(0)" ::: "memory");
    __builtin_amdgcn_s_setprio(1);
#pragma unroll
    for (int mi = 0; mi < 4; ++mi)
#pragma unroll
      for (int ni = 0; ni < 2; ++ni)
#pragma unroll
        for (int ks = 0; ks < 2; ++ks)
          acc[4 + mi][ni] = __builtin_amdgcn_mfma_f32_16x16x32_bf16(
              af[mi][ks], bv[ni][ks], acc[4 + mi][ni], 0, 0, 0);
    __builtin_amdgcn_s_setprio(0);
    if (t + 2 < NT)
      asm volatile("s_waitcnt vmcnt(6)" ::: "memory");
    else if (t + 1 < NT)
      asm volatile("s_waitcnt vmcnt(2)" ::: "memory");
    __builtin_amdgcn_s_barrier();
  }
#undef STAGE_AH
#undef STAGE_BF

#pragma unroll
  for (int mh = 0; mh < 2; ++mh)
#pragma unroll
    for (int mi = 0; mi < 4; ++mi) {
      const int row = m0 + mh * 128 + wm_ * 64 + mi * 16 + quad * 4;
#pragma unroll
      for (int reg = 0; reg < 4; ++reg) {
#pragma unroll
        for (int ni = 0; ni < 2; ++ni) {
          const int cc = n0 + wn_ * 32 + ni * 16 + col;
          if (F32OUT)
            ((float*)Cv)[(size_t)(row + reg) * ldc + cc] =
                acc[mh * 4 + mi][ni][reg];
          else
            ((u16*)Cv)[(size_t)(row + reg) * ldc + cc] =
                f2bf(acc[mh * 4 + mi][ni][reg]);
        }
      }
    }
}

// MFMA flash attention, transposed-S. R17: QBLK=128, 8 waves, grid
// (16 qt x 64 bh) with qt descending. Wave w owns q cols q0+w*16..+15.
// K-tiles of 64 keys, kt in [0, 2qt+1]; Ks dbuf (XOR-swizzled, DMA'd, wave
// w stages its 8 rows); Vt staged by waves 0-3 (256 threads, perm packs);
// Ps per-wave band roundtrip. Wave-level skip of fully-masked tiles.
__global__ __launch_bounds__(512) void attn_fwd(u16* __restrict__ qkv) {
  __shared__ u16 Ks[2][64 * 64];  // dbuf; row-linear, 16B-chunk XOR-swizzled
  __shared__ u16 Vt[64][68];      // [dim][key]; stride 34 dwords = 2 mod 32
  __shared__ u16 Ps[128][68];     // [q][key]
  const int tid = threadIdx.x;
  const int w = tid >> 6, lane = tid & 63;
  const int col = lane & 15, quad = lane >> 4;
  const int bh = blockIdx.y;
  const int b = bh >> 4, h = bh & 15;
  const int qt = 15 - blockIdx.x;  // descending work (LPT-ish dispatch)
  const int q0 = qt << 7;          // 128 q rows per block
  const int ktmax = 2 * qt + 1;
  const size_t base = (size_t)(b * kT) * kNq + h * 64;

  // K staging: wave w stages rows w*8..w*8+7 with ONE 1KB DMA. LDS dest
  // linear; per-lane global chunk XOR-swizzled (chunk c of row r holds
  // logical chunk c^(r&7); row&7 == krr here since w*8 is 8-aligned).
  const int krr = lane >> 3;
  const int ksw = (lane & 7) ^ krr;
  const u16* const kgbase =
      qkv + base + kD + (size_t)(w * 8 + krr) * kNq + ksw * 8;

  // V staging: waves 0-3 (tid<256), same scheme as before
  const int vkp = (tid & 31) * 2, vd0 = (tid >> 5) * 8;
  const u16* const vgbase = qkv + base + 2 * kD + (size_t)vkp * kNq + vd0;

  bf16x8 onesf;  // all-ones B-frag: row-sum MFMA for the softmax denominator
#pragma unroll
  for (int i = 0; i < 8; ++i) onesf[i] = (short)0x3F80;

  // Q B-frags: B[n=q=q0+w*16+col][k=d], d-offset ks*32+quad*8
  bf16x8 aq[2];
#pragma unroll
  for (int ks = 0; ks < 2; ++ks)
    aq[ks] = *(const bf16x8*)(qkv + base + (size_t)(q0 + w * 16 + col) * kNq +
                              ks * 32 + quad * 8);

  // prologue: tile 0 K-DMA + V regs
  gload16(kgbase, &Ks[0][(w * 8) * 64]);
  uint4 va, vb;
  if (w < 4) {
    va = *(const uint4*)vgbase;
    vb = *(const uint4*)(vgbase + kNq);
  }

  f32x4 o[4];  // O[q=w*16+quad*4+reg][d=nt*16+col]
#pragma unroll
  for (int nt = 0; nt < 4; ++nt) o[nt] = (f32x4){0.f, 0.f, 0.f, 0.f};
  f32x4 o4 = (f32x4){0.f, 0.f, 0.f, 0.f};  // l for q=w*16+quad*4+reg

  for (int kt = 0; kt <= ktmax; ++kt) {
    const int cur = kt & 1;
    __syncthreads();  // drains K-DMA(kt)+V-loads(kt); prior tile reads done
    if (w < 4) {      // write Vt(kt): v_perm_b32 packs key-pair words
      const unsigned int* aw = (const unsigned int*)&va;
      const unsigned int* bw = (const unsigned int*)&vb;
#pragma unroll
      for (int i = 0; i < 4; ++i) {
        *(unsigned int*)&Vt[vd0 + 2 * i][vkp] =
            __builtin_amdgcn_perm(bw[i], aw[i], 0x05040100u);
        *(unsigned int*)&Vt[vd0 + 2 * i + 1][vkp] =
            __builtin_amdgcn_perm(bw[i], aw[i], 0x07060302u);
      }
    }
    __syncthreads();  // Vt(kt) + Ks[cur] visible to all waves

    if (kt < ktmax) {  // prefetch kt+1; latency hides under QK/softmax/PV
      const size_t ko = (size_t)((kt + 1) << 6) * kNq;
      gload16(kgbase + ko, &Ks[cur ^ 1][(w * 8) * 64]);
      if (w < 4) {
        va = *(const uint4*)(vgbase + ko);
        vb = *(const uint4*)(vgbase + ko + kNq);
      }
    }

    const int kb = (kt << 6) - q0;  // key offset relative to q0
    if (kb <= w * 16 + 15) {        // wave has at least one visible (q,k)
      // St = K Q^T : rows = 64 keys (4 nt frags), cols = wave's 16 q
      f32x4 st[4];
#pragma unroll
      for (int nt = 0; nt < 4; ++nt) st[nt] = (f32x4){0.f, 0.f, 0.f, 0.f};
#pragma unroll
      for (int ks = 0; ks < 2; ++ks) {
#pragma unroll
        for (int nt = 0; nt < 4; ++nt) {
          const int kr = nt * 16 + col;  // key row
          const bf16x8 bk =
              *(const bf16x8*)&Ks[cur][kr * 64 +
                                       (((ks * 4 + quad) ^ (col & 7)) * 8)];
          st[nt] = __builtin_amdgcn_mfma_f32_16x16x32_bf16(bk, aq[ks], st[nt],
                                                           0, 0, 0);
        }
      }

      // p = exp2(st); mask only when this wave's band crosses the diagonal
      if (kb + 63 > w * 16) {
        const int qrel = w * 16 + col;
#pragma unroll
        for (int nt = 0; nt < 4; ++nt)
#pragma unroll
          for (int reg = 0; reg < 4; ++reg) {
            const int krel = kb + nt * 16 + quad * 4 + reg;
            st[nt][reg] =
                (krel <= qrel) ? __builtin_amdgcn_exp2f(st[nt][reg]) : 0.f;
          }
      } else {
#pragma unroll
        for (int nt = 0; nt < 4; ++nt)
#pragma unroll
          for (int reg = 0; reg < 4; ++reg)
            st[nt][reg] = __builtin_amdgcn_exp2f(st[nt][reg]);
      }

      // P -> Ps[q][k]: per nt, 4 consecutive k -> one b64 write
#pragma unroll
      for (int nt = 0; nt < 4; ++nt) {
        uint2 pk;
        pk.x = cvtpk(st[nt][0], st[nt][1]);
        pk.y = cvtpk(st[nt][2], st[nt][3]);
        *(uint2*)&Ps[w * 16 + col][nt * 16 + quad * 4] = pk;
      }

      // O += P V; l += P 1 (same-wave Ps band roundtrip, no barrier needed)
#pragma unroll
      for (int ks = 0; ks < 2; ++ks) {
        const bf16x8 ap = *(const bf16x8*)&Ps[w * 16 + col][ks * 32 + quad * 8];
#pragma unroll
        for (int nt = 0; nt < 4; ++nt) {
          const bf16x8 bv =
              *(const bf16x8*)&Vt[nt * 16 + col][ks * 32 + quad * 8];
          o[nt] =
              __builtin_amdgcn_mfma_f32_16x16x32_bf16(ap, bv, o[nt], 0, 0, 0);
        }
        o4 = __builtin_amdgcn_mfma_f32_16x16x32_bf16(ap, onesf, o4, 0, 0, 0);
      }
    }
  }

  // epilogue: o row q = q0+w*16+quad*4+reg; l = o4[reg] (replicated over cols)
#pragma unroll
  for (int reg = 0; reg < 4; ++reg) {
    const float inv = 1.0f / o4[reg];
    u16* yp = qkv + base + (size_t)(q0 + w * 16 + quad * 4 + reg) * kNq;
#pragma unroll
    for (int nt = 0; nt < 4; ++nt) yp[nt * 16 + col] = f2bf(o[nt][reg] * inv);
  }
}

extern "C" void kernel_launch(void* const* d_in, const int* in_sizes, int n_in,
                              void* d_out, int out_size, void* d_ws,
                              size_t ws_size, hipStream_t stream) {
  const float* x = (const float*)d_in[0];      // [8192][1024] fp32
  const float* w_qkv = (const float*)d_in[1];  // [1024][3072] fp32
  const float* w_out = (const float*)d_in[2];  // [1024][1024] fp32

  u16* wqkvT = (u16*)d_ws;                // [3072][1024] bf16  6.3MB
  u16* woutT = wqkvT + (size_t)kNq * kD;  // [1024][1024] bf16  2.1MB
  u16* qkvb = woutT + (size_t)kD * kD;    // [8192][3072] bf16 50.3MB
  u16* xb = (u16*)d_out;  // x as bf16 in d_out bytes (dead after qkv gemm)

  prep<<<8192, 256, 0, stream>>>(x, xb, w_qkv, wqkvT, w_out, woutT);
  gemm256b<false><<<dim3(kNq / 256, kM / 256), 512, 0, stream>>>(xb, wqkvT,
                                                                 qkvb, kD,
                                                                 kNq);
  attn_fwd<<<dim3(16, kB * kH), 512, 0, stream>>>(qkvb);
  gemm_mt<true><<<dim3(kD / 128, kM / 256), 512, 0, stream>>>(qkvb, woutT,
                                                              d_out, kNq, kD);
}

// Round 9
// 235.933 us; speedup vs baseline: 1.1208x; 1.1208x over previous
//
#include <hip/hip_runtime.h>
#include <hip/hip_bf16.h>

// CausalSelfAttention: B=4, T=2048, D=1024, H=16, DH=64.
// Dtypes (established): inputs fp32, output fp32 (absmax thresh 0.075).
// R18: revert attn to R16 structure (R17's QBLK=128 tripled HBM fetch
// 34.6->113MB and broke balance: 102us). Restored: QBLK=64, 4 waves,
// pa/31-pa paired blocks (uniform 33 tiles), Ks dbuf XOR-swizzled DMA,
// Vt/Ps pad 68 (conflicts 0), grid (64 bh x 16 pa). Kept from R17: fused
// prep (6->4 launches). GEMMs: gemm256b (gemm1) + gemm_mt (gemm2), as R16.

namespace {
constexpr int kB = 4, kT = 2048, kD = 1024, kH = 16;
constexpr int kM = kB * kT;  // 8192
constexpr int kNq = 3 * kD;  // 3072
constexpr float kS = 0.180336880f;  // log2(e)/sqrt(64), folded into Q weights
}  // namespace

typedef unsigned short u16;
typedef short bf16x8 __attribute__((ext_vector_type(8)));  // 8 bf16, 4 VGPR
typedef float f32x4 __attribute__((ext_vector_type(4)));

__device__ __forceinline__ u16 f2bf(float f) {
  unsigned int u = __float_as_uint(f);
  u += 0x7fffu + ((u >> 16) & 1u);  // round-to-nearest-even
  return (u16)(u >> 16);
}
__device__ __forceinline__ unsigned int pack2(float a, float b) {
  return (unsigned int)f2bf(a) | ((unsigned int)f2bf(b) << 16);
}
// packed f32x2 -> bf16x2 in one VALU op (RNE)
__device__ __forceinline__ unsigned int cvtpk(float a, float b) {
  unsigned int r;
  asm("v_cvt_pk_bf16_f32 %0, %1, %2" : "=v"(r) : "v"(a), "v"(b));
  return r;
}

// async 16B global -> LDS (wave-uniform base + lane*16 semantics)
__device__ __forceinline__ void gload16(const u16* g, u16* l) {
  __builtin_amdgcn_global_load_lds(
      (const __attribute__((address_space(1))) unsigned int*)(uintptr_t)g,
      (__attribute__((address_space(3))) unsigned int*)(uintptr_t)l, 16, 0, 0);
}

// Fused prep: blocks [0,4096) x->bf16 cvt; [4096,7168) w_qkv transpose
// (kS-folded on Q cols); [7168,8192) w_out transpose.
__global__ __launch_bounds__(256) void prep(const float* __restrict__ x,
                                            u16* __restrict__ xb,
                                            const float* __restrict__ wq,
                                            u16* __restrict__ wqT,
                                            const float* __restrict__ wo,
                                            u16* __restrict__ woT) {
  __shared__ float T[32][33];
  const int tid = threadIdx.x;
  const int id = blockIdx.x;
  if (id < 4096) {  // cvt: 8 elems/thread
    const size_t i = ((size_t)id * 256 + tid) * 8;
    const float4 v0 = *(const float4*)(x + i);
    const float4 v1 = *(const float4*)(x + i + 4);
    uint4 p;
    p.x = pack2(v0.x, v0.y);
    p.y = pack2(v0.z, v0.w);
    p.z = pack2(v1.x, v1.y);
    p.w = pack2(v1.z, v1.w);
    *(uint4*)(xb + i) = p;
    return;
  }
  const float* W;
  u16* WT;
  int N, nscale, nb, kb;
  if (id < 4096 + 3072) {
    const int t = id - 4096;  // grid (96, 32)
    W = wq; WT = wqT; N = kNq; nscale = kD;
    nb = (t % 96) * 32; kb = (t / 96) * 32;
  } else {
    const int t = id - 7168;  // grid (32, 32)
    W = wo; WT = woT; N = kD; nscale = 0;
    nb = (t & 31) * 32; kb = (t >> 5) * 32;
  }
  const int r = tid >> 3, c = (tid & 7) * 4;
  const float4 v = *(const float4*)&W[(size_t)(kb + r) * N + nb + c];
  T[r][c + 0] = v.x;
  T[r][c + 1] = v.y;
  T[r][c + 2] = v.z;
  T[r][c + 3] = v.w;
  __syncthreads();
  const float s = (nb + r < nscale) ? kS : 1.0f;
  uint2 p;
  p.x = pack2(T[c + 0][r] * s, T[c + 1][r] * s);
  p.y = pack2(T[c + 2][r] * s, T[c + 3][r] * s);
  *(uint2*)&WT[(size_t)(nb + r) * kD + kb + c] = p;
}

// ---------------------------------------------------------------------------
// gemm256b: 256x256 block, 8 waves x (128x64) wave tile (unchanged from R16).
// ---------------------------------------------------------------------------
template <bool F32OUT>
__global__ __launch_bounds__(512, 2) void gemm256b(const u16* __restrict__ A,
                                                   const u16* __restrict__ BT,
                                                   void* __restrict__ Cv,
                                                   int lda, int ldc) {
  __shared__ u16 As[2][256 * 64];
  __shared__ u16 Bs[2][256 * 64];
  constexpr int NT = kD / 64;  // 16 K-tiles
  const int tid = threadIdx.x;
  const int wid = tid >> 6, lane = tid & 63;
  const int col = lane & 15, quad = lane >> 4;
  const int wm_ = wid >> 2, wn_ = wid & 3;  // 2(M) x 4(N) waves

  const int nwg = gridDim.x * gridDim.y;
  int flat = blockIdx.y * gridDim.x + blockIdx.x;
  flat = (flat & 7) * (nwg >> 3) + (flat >> 3);
  const int n0 = (flat % gridDim.x) * 256;
  const int m0 = (flat / gridDim.x) * 256;

  const int srow = tid >> 3;                      // 0..63
  const int scol8 = (tid & 7) * 8;                // storage chunk (elems)
  const int gch8 = ((tid & 7) ^ (srow & 7)) * 8;  // swizzled global chunk
  const u16* const Ag = A + (size_t)(m0 + srow) * lda + gch8;
  const u16* const Bg = BT + (size_t)(n0 + srow) * kD + gch8;

  f32x4 acc[8][4];
#pragma unroll
  for (int i = 0; i < 8; ++i)
#pragma unroll
    for (int j = 0; j < 4; ++j) acc[i][j] = (f32x4){0.f, 0.f, 0.f, 0.f};

#define STAGE_AH(buf, half, k0)                                      \
  do {                                                               \
    gload16(Ag + (size_t)((half)*128) * lda + (k0),                  \
            &As[buf][((half)*128 + srow) * 64 + scol8]);             \
    gload16(Ag + (size_t)((half)*128 + 64) * lda + (k0),             \
            &As[buf][((half)*128 + 64 + srow) * 64 + scol8]);        \
  } while (0)
#define STAGE_BH(buf, half, k0)                                      \
  do {                                                               \
    gload16(Bg + (size_t)((half)*128) * kD + (k0),                   \
            &Bs[buf][((half)*128 + srow) * 64 + scol8]);             \
    gload16(Bg + (size_t)((half)*128 + 64) * kD + (k0),              \
            &Bs[buf][((half)*128 + 64 + srow) * 64 + scol8]);        \
  } while (0)

  // prologue: AT0,BT0,BB0 complete; AB0 (2 loads) left in flight
  STAGE_AH(0, 0, 0);
  STAGE_BH(0, 0, 0);
  STAGE_BH(0, 1, 0);
  STAGE_AH(0, 1, 0);
  asm volatile("s_waitcnt vmcnt(2)" ::: "memory");
  __builtin_amdgcn_s_barrier();

  for (int t = 0; t < NT; ++t) {
    const int cur = t & 1, nxt = cur ^ 1;
    const u16* Ac = &As[cur][0];
    const u16* Bc = &Bs[cur][0];
    const int k1 = (t + 1) * 64;
    const bool pf = (t + 1 < NT);
    bf16x8 af[4], bv[4];

#define READ_A(KS, MH)                                                        \
  do {                                                                        \
    _Pragma("unroll") for (int mi = 0; mi < 4; ++mi) {                        \
      const int r = (MH)*128 + wm_ * 64 + mi * 16 + col;                      \
      af[mi] =                                                                \
          *(const bf16x8*)&Ac[r * 64 + ((((KS)*4 + quad) ^ (r & 7)) * 8)];    \
    }                                                                         \
  } while (0)
#define READ_B(KS)                                                            \
  do {                                                                        \
    _Pragma("unroll") for (int ni = 0; ni < 4; ++ni) {                        \
      const int r = wn_ * 64 + ni * 16 + col;                                 \
      bv[ni] =                                                                \
          *(const bf16x8*)&Bc[r * 64 + ((((KS)*4 + quad) ^ (r & 7)) * 8)];    \
    }                                                                         \
  } while (0)
#define MFMA16(MH)                                                            \
  do {                                                                        \
    __builtin_amdgcn_s_setprio(1);                                            \
    _Pragma("unroll") for (int mi = 0; mi < 4; ++mi)                          \
        _Pragma("unroll") for (int ni = 0; ni < 4; ++ni) acc[(MH)*4 + mi][ni] \
        = __builtin_amdgcn_mfma_f32_16x16x32_bf16(af[mi], bv[ni],             \
                                                  acc[(MH)*4 + mi][ni], 0, 0, \
                                                  0);                         \
    __builtin_amdgcn_s_setprio(0);                                            \
  } while (0)

    // P0: ks0, M-half0, +B(ks0); stage AT(t+1)
    READ_A(0, 0);
    READ_B(0);
    if (pf) STAGE_AH(nxt, 0, k1);
    __builtin_amdgcn_s_barrier();
    asm volatile("s_waitcnt lgkmcnt(0)" ::: "memory");
    MFMA16(0);
    if (pf)
      asm volatile("s_waitcnt vmcnt(2)" ::: "memory");  // AB(t) ready
    else
      asm volatile("s_waitcnt vmcnt(0)" ::: "memory");
    __builtin_amdgcn_s_barrier();

    // P1: ks0, M-half1 (reuse bv); stage BT(t+1)
    READ_A(0, 1);
    if (pf) STAGE_BH(nxt, 0, k1);
    __builtin_amdgcn_s_barrier();
    asm volatile("s_waitcnt lgkmcnt(0)" ::: "memory");
    MFMA16(1);
    __builtin_amdgcn_s_barrier();

    // P2: ks1, M-half0, +B(ks1); stage BB(t+1)
    READ_A(1, 0);
    READ_B(1);
    if (pf) STAGE_BH(nxt, 1, k1);
    __builtin_amdgcn_s_barrier();
    asm volatile("s_waitcnt lgkmcnt(0)" ::: "memory");
    MFMA16(0);
    __builtin_amdgcn_s_barrier();

    // P3: ks1, M-half1; stage AB(t+1)
    READ_A(1, 1);
    if (pf) STAGE_AH(nxt, 1, k1);
    __builtin_amdgcn_s_barrier();
    asm volatile("s_waitcnt lgkmcnt(0)" ::: "memory");
    MFMA16(1);
    if (pf)
      asm volatile("s_waitcnt vmcnt(2)" ::: "memory");  // AT,BT,BB(t+1) done
    __builtin_amdgcn_s_barrier();

#undef READ_A
#undef READ_B
#undef MFMA16
  }
#undef STAGE_AH
#undef STAGE_BH

#pragma unroll
  for (int mig = 0; mig < 8; ++mig) {
    const int row =
        m0 + (mig >> 2) * 128 + wm_ * 64 + (mig & 3) * 16 + quad * 4;
#pragma unroll
    for (int reg = 0; reg < 4; ++reg) {
#pragma unroll
      for (int nig = 0; nig < 4; ++nig) {
        const int cc = n0 + wn_ * 64 + nig * 16 + col;
        if (F32OUT)
          ((float*)Cv)[(size_t)(row + reg) * ldc + cc] = acc[mig][nig][reg];
        else
          ((u16*)Cv)[(size_t)(row + reg) * ldc + cc] = f2bf(acc[mig][nig][reg]);
      }
    }
  }
}

// ---------------------------------------------------------------------------
// 256(M)x128(N) 8-wave GEMM (unchanged from R14) -- gemm2 (256 blocks).
// ---------------------------------------------------------------------------
template <bool F32OUT>
__global__ __launch_bounds__(512, 2) void gemm_mt(const u16* __restrict__ A,
                                                  const u16* __restrict__ BT,
                                                  void* __restrict__ Cv,
                                                  int lda, int ldc) {
  __shared__ u16 As[2][256 * 64];
  __shared__ u16 Bs[2][128 * 64];
  constexpr int NT = kD / 64;  // 16 K-tiles
  const int tid = threadIdx.x;
  const int wid = tid >> 6, lane = tid & 63;
  const int col = lane & 15, quad = lane >> 4;
  const int wm_ = wid >> 2, wn_ = wid & 3;

  const int nwg = gridDim.x * gridDim.y;
  int flat = blockIdx.y * gridDim.x + blockIdx.x;
  flat = (flat & 7) * (nwg >> 3) + (flat >> 3);
  const int n0 = (flat % gridDim.x) * 128;
  const int m0 = (flat / gridDim.x) * 256;

  const int srow = tid >> 3;                      // 0..63
  const int scol8 = (tid & 7) * 8;                // storage chunk (elems)
  const int gch8 = ((tid & 7) ^ (srow & 7)) * 8;  // swizzled global chunk
  const u16* const Ag = A + (size_t)(m0 + srow) * lda + gch8;
  const u16* const Bg = BT + (size_t)(n0 + srow) * kD + gch8;

  f32x4 acc[8][2];
#pragma unroll
  for (int i = 0; i < 8; ++i)
#pragma unroll
    for (int j = 0; j < 2; ++j) acc[i][j] = (f32x4){0.f, 0.f, 0.f, 0.f};

#define STAGE_AH(buf, half, k0)                                      \
  do {                                                               \
    gload16(Ag + (size_t)((half)*128) * lda + (k0),                  \
            &As[buf][((half)*128 + srow) * 64 + scol8]);             \
    gload16(Ag + (size_t)((half)*128 + 64) * lda + (k0),             \
            &As[buf][((half)*128 + 64 + srow) * 64 + scol8]);        \
  } while (0)
#define STAGE_BF(buf, k0)                                            \
  do {                                                               \
    gload16(Bg + (size_t)(k0), &Bs[buf][srow * 64 + scol8]);         \
    gload16(Bg + (size_t)64 * kD + (k0),                             \
            &Bs[buf][(64 + srow) * 64 + scol8]);                     \
  } while (0)

  STAGE_AH(0, 0, 0);
  STAGE_BF(0, 0);
  STAGE_AH(0, 1, 0);
  STAGE_AH(1, 0, 64);
  STAGE_BF(1, 64);
  asm volatile("s_waitcnt vmcnt(4)" ::: "memory");
  __builtin_amdgcn_s_barrier();

  for (int t = 0; t < NT; ++t) {
    const int cur = t & 1;
    const u16* Ac = &As[cur][0];
    const u16* Bc = &Bs[cur][0];
    bf16x8 af[4][2], bv[2][2];

#pragma unroll
    for (int mi = 0; mi < 4; ++mi) {
      const int r = wm_ * 64 + mi * 16 + col;
#pragma unroll
      for (int ks = 0; ks < 2; ++ks)
        af[mi][ks] =
            *(const bf16x8*)&Ac[r * 64 + (((ks * 4 + quad) ^ (r & 7)) * 8)];
    }
#pragma unroll
    for (int ni = 0; ni < 2; ++ni) {
      const int r = wn_ * 32 + ni * 16 + col;
#pragma unroll
      for (int ks = 0; ks < 2; ++ks)
        bv[ni][ks] =
            *(const bf16x8*)&Bc[r * 64 + (((ks * 4 + quad) ^ (r & 7)) * 8)];
    }
    if (t + 1 < NT) STAGE_AH(cur ^ 1, 1, (t + 1) * 64);
    __builtin_amdgcn_s_barrier();
    asm volatile("s_waitcnt lgkmcnt(0)" ::: "memory");
    __builtin_amdgcn_s_setprio(1);
#pragma unroll
    for (int mi = 0; mi < 4; ++mi)
#pragma unroll
      for (int ni = 0; ni < 2; ++ni)
#pragma unroll
        for (int ks = 0; ks < 2; ++ks)
          acc[mi][ni] = __builtin_amdgcn_mfma_f32_16x16x32_bf16(
              af[mi][ks], bv[ni][ks], acc[mi][ni], 0, 0, 0);
    __builtin_amdgcn_s_setprio(0);
    if (t + 1 < NT)
      asm volatile("s_waitcnt vmcnt(6)" ::: "memory");
    else
      asm volatile("s_waitcnt vmcnt(0)" ::: "memory");
    __builtin_amdgcn_s_barrier();

#pragma unroll
    for (int mi = 0; mi < 4; ++mi) {
      const int r = 128 + wm_ * 64 + mi * 16 + col;
#pragma unroll
      for (int ks = 0; ks < 2; ++ks)
        af[mi][ks] =
            *(const bf16x8*)&Ac[r * 64 + (((ks * 4 + quad) ^ (r & 7)) * 8)];
    }
    if (t + 2 < NT) {
      STAGE_AH(cur, 0, (t + 2) * 64);
      STAGE_BF(cur, (t + 2) * 64);
    }
    __builtin_amdgcn_s_barrier();
    asm volatile("s_waitcnt lgkmcnt(0)" ::: "memory");
    __builtin_amdgcn_s_setprio(1);
#pragma unroll
    for (int mi = 0; mi < 4; ++mi)
#pragma unroll
      for (int ni = 0; ni < 2; ++ni)
#pragma unroll
        for (int ks = 0; ks < 2; ++ks)
          acc[4 + mi][ni] = __builtin_amdgcn_mfma_f32_16x16x32_bf16(
              af[mi][ks], bv[ni][ks], acc[4 + mi][ni], 0, 0, 0);
    __builtin_amdgcn_s_setprio(0);
    if (t + 2 < NT)
      asm volatile("s_waitcnt vmcnt(6)" ::: "memory");
    else if (t + 1 < NT)
      asm volatile("s_waitcnt vmcnt(2)" ::: "memory");
    __builtin_amdgcn_s_barrier();
  }
#undef STAGE_AH
#undef STAGE_BF

#pragma unroll
  for (int mh = 0; mh < 2; ++mh)
#pragma unroll
    for (int mi = 0; mi < 4; ++mi) {
      const int row = m0 + mh * 128 + wm_ * 64 + mi * 16 + quad * 4;
#pragma unroll
      for (int reg = 0; reg < 4; ++reg) {
#pragma unroll
        for (int ni = 0; ni < 2; ++ni) {
          const int cc = n0 + wn_ * 32 + ni * 16 + col;
          if (F32OUT)
            ((float*)Cv)[(size_t)(row + reg) * ldc + cc] =
                acc[mh * 4 + mi][ni][reg];
          else
            ((u16*)Cv)[(size_t)(row + reg) * ldc + cc] =
                f2bf(acc[mh * 4 + mi][ni][reg]);
        }
      }
    }
}

// MFMA flash attention, transposed-S (R16 structure restored).
__global__ __launch_bounds__(256) void attn_fwd(u16* __restrict__ qkv) {
  __shared__ u16 Ks[2][64 * 64];  // dbuf; row-linear, 16B-chunk XOR-swizzled
  __shared__ u16 Vt[64][68];      // [dim][key]; stride 34 dwords = 2 mod 32
  __shared__ u16 Ps[64][68];      // [q][key]
  const int tid = threadIdx.x;
  const int w = tid >> 6, lane = tid & 63;
  const int col = lane & 15, quad = lane >> 4;
  const int bh = blockIdx.x;
  const int b = bh >> 4, h = bh & 15;
  const int pa = blockIdx.y;  // 0..15
  const size_t base = (size_t)(b * kT) * kNq + h * 64;

  const int krr = lane >> 3;
  const int ksw = (lane & 7) ^ krr;
  const u16* const kgbase =
      qkv + base + kD + (size_t)(w * 16 + krr) * kNq + ksw * 8;

  const int vkp = (tid & 31) * 2, vd0 = (tid >> 5) * 8;  // V staging
  const u16* const vgbase = qkv + base + 2 * kD + (size_t)vkp * kNq + vd0;

  bf16x8 onesf;  // all-ones B-frag: row-sum MFMA for the softmax denominator
#pragma unroll
  for (int i = 0; i < 8; ++i) onesf[i] = (short)0x3F80;

  int cur = 0;
#pragma unroll
  for (int pass = 0; pass < 2; ++pass) {
    const int qt = pass ? (31 - pa) : pa;
    const int q0 = qt << 6;

    bf16x8 aq[2];
#pragma unroll
    for (int ks = 0; ks < 2; ++ks)
      aq[ks] = *(const bf16x8*)(qkv + base + (size_t)(q0 + w * 16 + col) * kNq +
                                ks * 32 + quad * 8);

    gload16(kgbase, &Ks[cur][(w * 16) * 64]);
    gload16(kgbase + (size_t)8 * kNq, &Ks[cur][(w * 16 + 8) * 64]);
    uint4 va = *(const uint4*)vgbase;
    uint4 vb = *(const uint4*)(vgbase + kNq);

    f32x4 o[4];  // O[q=w*16+quad*4+reg][d=nt*16+col]
#pragma unroll
    for (int nt = 0; nt < 4; ++nt) o[nt] = (f32x4){0.f, 0.f, 0.f, 0.f};
    f32x4 o4 = (f32x4){0.f, 0.f, 0.f, 0.f};  // l for q=w*16+quad*4+reg

    for (int kt = 0; kt <= qt; ++kt) {
      __syncthreads();  // drains K-DMA(kt)+V-loads(kt); prior tile reads done
      {  // write Vt(kt): v_perm_b32 packs key-pair words
        const unsigned int* aw = (const unsigned int*)&va;
        const unsigned int* bw = (const unsigned int*)&vb;
#pragma unroll
        for (int i = 0; i < 4; ++i) {
          *(unsigned int*)&Vt[vd0 + 2 * i][vkp] =
              __builtin_amdgcn_perm(bw[i], aw[i], 0x05040100u);
          *(unsigned int*)&Vt[vd0 + 2 * i + 1][vkp] =
              __builtin_amdgcn_perm(bw[i], aw[i], 0x07060302u);
        }
      }
      __syncthreads();  // Vt(kt) + Ks[cur] visible to all waves

      if (kt < qt) {  // prefetch kt+1; latency hides under QK/softmax/PV
        const size_t ko = (size_t)((kt + 1) << 6) * kNq;
        gload16(kgbase + ko, &Ks[cur ^ 1][(w * 16) * 64]);
        gload16(kgbase + ko + (size_t)8 * kNq, &Ks[cur ^ 1][(w * 16 + 8) * 64]);
        va = *(const uint4*)(vgbase + ko);
        vb = *(const uint4*)(vgbase + ko + kNq);
      }

      // St = K Q^T : rows = 64 keys (4 nt frags), cols = wave's 16 q
      f32x4 st[4];
#pragma unroll
      for (int nt = 0; nt < 4; ++nt) st[nt] = (f32x4){0.f, 0.f, 0.f, 0.f};
#pragma unroll
      for (int ks = 0; ks < 2; ++ks) {
#pragma unroll
        for (int nt = 0; nt < 4; ++nt) {
          const int kr = nt * 16 + col;  // key row
          const bf16x8 bk =
              *(const bf16x8*)&Ks[cur][kr * 64 +
                                       (((ks * 4 + quad) ^ (col & 7)) * 8)];
          st[nt] = __builtin_amdgcn_mfma_f32_16x16x32_bf16(bk, aq[ks], st[nt],
                                                           0, 0, 0);
        }
      }

      // p = exp2(st) via raw hw exp2 (bounded logits); mask diagonal tile
      if (kt == qt) {
        const int qrel = w * 16 + col;
#pragma unroll
        for (int nt = 0; nt < 4; ++nt)
#pragma unroll
          for (int reg = 0; reg < 4; ++reg) {
            const int krel = nt * 16 + quad * 4 + reg;
            st[nt][reg] =
                (krel <= qrel) ? __builtin_amdgcn_exp2f(st[nt][reg]) : 0.f;
          }
      } else {
#pragma unroll
        for (int nt = 0; nt < 4; ++nt)
#pragma unroll
          for (int reg = 0; reg < 4; ++reg)
            st[nt][reg] = __builtin_amdgcn_exp2f(st[nt][reg]);
      }

      // P -> Ps[q][k]: per nt, 4 consecutive k -> one b64 write (cvt_pk pack)
#pragma unroll
      for (int nt = 0; nt < 4; ++nt) {
        uint2 pk;
        pk.x = cvtpk(st[nt][0], st[nt][1]);
        pk.y = cvtpk(st[nt][2], st[nt][3]);
        *(uint2*)&Ps[w * 16 + col][nt * 16 + quad * 4] = pk;
      }

      // O += P V; l += P 1 (same-wave Ps band roundtrip, no barrier needed)
#pragma unroll
      for (int ks = 0; ks < 2; ++ks) {
        const bf16x8 ap =
            *(const bf16x8*)&Ps[w * 16 + col][ks * 32 + quad * 8];
#pragma unroll
        for (int nt = 0; nt < 4; ++nt) {
          const bf16x8 bv =
              *(const bf16x8*)&Vt[nt * 16 + col][ks * 32 + quad * 8];
          o[nt] = __builtin_amdgcn_mfma_f32_16x16x32_bf16(ap, bv, o[nt], 0, 0,
                                                          0);
        }
        o4 = __builtin_amdgcn_mfma_f32_16x16x32_bf16(ap, onesf, o4, 0, 0, 0);
      }
      cur ^= 1;
    }

    // epilogue: o row q = w*16+quad*4+reg; l = o4[reg] (replicated over cols)
#pragma unroll
    for (int reg = 0; reg < 4; ++reg) {
      const float inv = 1.0f / o4[reg];
      u16* yp = qkv + base + (size_t)(q0 + w * 16 + quad * 4 + reg) * kNq;
#pragma unroll
      for (int nt = 0; nt < 4; ++nt)
        yp[nt * 16 + col] = f2bf(o[nt][reg] * inv);
    }
  }
}

extern "C" void kernel_launch(void* const* d_in, const int* in_sizes, int n_in,
                              void* d_out, int out_size, void* d_ws,
                              size_t ws_size, hipStream_t stream) {
  const float* x = (const float*)d_in[0];      // [8192][1024] fp32
  const float* w_qkv = (const float*)d_in[1];  // [1024][3072] fp32
  const float* w_out = (const float*)d_in[2];  // [1024][1024] fp32

  u16* wqkvT = (u16*)d_ws;                // [3072][1024] bf16  6.3MB
  u16* woutT = wqkvT + (size_t)kNq * kD;  // [1024][1024] bf16  2.1MB
  u16* qkvb = woutT + (size_t)kD * kD;    // [8192][3072] bf16 50.3MB
  u16* xb = (u16*)d_out;  // x as bf16 in d_out bytes (dead after qkv gemm)

  prep<<<8192, 256, 0, stream>>>(x, xb, w_qkv, wqkvT, w_out, woutT);
  gemm256b<false><<<dim3(kNq / 256, kM / 256), 512, 0, stream>>>(xb, wqkvT,
                                                                 qkvb, kD,
                                                                 kNq);
  attn_fwd<<<dim3(kB * kH, 16), 256, 0, stream>>>(qkvb);
  gemm_mt<true><<<dim3(kD / 128, kM / 256), 512, 0, stream>>>(qkvb, woutT,
                                                              d_out, kNq, kD);
}